// Round 4
// baseline (90.443 us; speedup 1.0000x reference)
//
#include <hip/hip_runtime.h>

// GlobalAttention: out = softmax_j(scores) @ H
// scores[i,j] = sum_m lrelu(Wh1[i,m]+Wh2[j,m]) * a[m]
// lrelu(t) = 0.6 t + 0.4|t|; row-constant part drops out of softmax:
// scores'[i,j] = s2[j] + sum_m b[m]*|Wh1[i,m]+Wh2[j,m]|,  b[m]=0.4*a[m].
//
// R4 structure: LDS-issue-bound fix. Only 16-unique-address operands live in
// LDS; 4-unique (i-side) operands read direct from global (coalescer dedup,
// L2-resident tiles). HT = H^T precomputed so k4's j-axis vectorizes.
// PAD 65 (== 1 mod 32): 16 rows at stride 4 -> 2-way bank aliasing = free.

#define PAD 65

// ---------- kT: HT[c][j] = H[j][c]  (H 1024x256 -> HT 256x1024)
__global__ __launch_bounds__(256) void kT_transpose(const float* __restrict__ H,
                                                    float* __restrict__ HT) {
    __shared__ float tile[64][PAD];
    const int bj = blockIdx.x;  // j-tile 0..15
    const int bc = blockIdx.y;  // c-tile 0..3
    const int t = threadIdx.x;
    const int lr = t >> 2, lc = (t & 3) * 16;
#pragma unroll
    for (int q = 0; q < 4; ++q) {
        *(float4*)&tile[lr][lc + q * 4] =
            *(const float4*)&H[(bj * 64 + lr) * 256 + bc * 64 + lc + q * 4];
    }
    __syncthreads();
#pragma unroll
    for (int q = 0; q < 4; ++q) {
        float4 v = make_float4(tile[lc + q * 4 + 0][lr], tile[lc + q * 4 + 1][lr],
                               tile[lc + q * 4 + 2][lr], tile[lc + q * 4 + 3][lr]);
        *(float4*)&HT[(bc * 64 + lr) * 1024 + bj * 64 + lc + q * 4] = v;
    }
}

// ---------- K1: Wh[i][m] = sum_k H[i][k]*Wre[m][k], LDS-free.
// Wre[m][k] = W[m&255][(m>>8)*256+k]. Tile 32i x 64m, thread 2i x 4m.
// Grid (32,8)=256 blocks. A-loads 4-unique/wave, B-loads 16-unique/wave.
__global__ __launch_bounds__(256) void k1_gemm_wh(const float* __restrict__ H,
                                                  const float* __restrict__ W,
                                                  float* __restrict__ Wh) {
    const int t = threadIdx.x;
    const int ti = t >> 4, tj = t & 15;
    const int i0 = blockIdx.x * 32 + ti * 2;
    const int m0 = blockIdx.y * 64 + tj * 4;
    const int wrow = m0 & 255;
    const int half = m0 >> 8;
    const float* A0 = H + (size_t)i0 * 256;
    const float* A1 = A0 + 256;
    const float* B = W + (size_t)wrow * 512 + half * 256;
    float acc[2][4] = {};
#pragma unroll 4
    for (int k = 0; k < 256; k += 4) {
        float4 a0 = *(const float4*)&A0[k];
        float4 a1 = *(const float4*)&A1[k];
        float4 b0 = *(const float4*)&B[k];
        float4 b1 = *(const float4*)&B[512 + k];
        float4 b2 = *(const float4*)&B[1024 + k];
        float4 b3 = *(const float4*)&B[1536 + k];
        acc[0][0] = fmaf(a0.x, b0.x, acc[0][0]); acc[0][0] = fmaf(a0.y, b0.y, acc[0][0]);
        acc[0][0] = fmaf(a0.z, b0.z, acc[0][0]); acc[0][0] = fmaf(a0.w, b0.w, acc[0][0]);
        acc[0][1] = fmaf(a0.x, b1.x, acc[0][1]); acc[0][1] = fmaf(a0.y, b1.y, acc[0][1]);
        acc[0][1] = fmaf(a0.z, b1.z, acc[0][1]); acc[0][1] = fmaf(a0.w, b1.w, acc[0][1]);
        acc[0][2] = fmaf(a0.x, b2.x, acc[0][2]); acc[0][2] = fmaf(a0.y, b2.y, acc[0][2]);
        acc[0][2] = fmaf(a0.z, b2.z, acc[0][2]); acc[0][2] = fmaf(a0.w, b2.w, acc[0][2]);
        acc[0][3] = fmaf(a0.x, b3.x, acc[0][3]); acc[0][3] = fmaf(a0.y, b3.y, acc[0][3]);
        acc[0][3] = fmaf(a0.z, b3.z, acc[0][3]); acc[0][3] = fmaf(a0.w, b3.w, acc[0][3]);
        acc[1][0] = fmaf(a1.x, b0.x, acc[1][0]); acc[1][0] = fmaf(a1.y, b0.y, acc[1][0]);
        acc[1][0] = fmaf(a1.z, b0.z, acc[1][0]); acc[1][0] = fmaf(a1.w, b0.w, acc[1][0]);
        acc[1][1] = fmaf(a1.x, b1.x, acc[1][1]); acc[1][1] = fmaf(a1.y, b1.y, acc[1][1]);
        acc[1][1] = fmaf(a1.z, b1.z, acc[1][1]); acc[1][1] = fmaf(a1.w, b1.w, acc[1][1]);
        acc[1][2] = fmaf(a1.x, b2.x, acc[1][2]); acc[1][2] = fmaf(a1.y, b2.y, acc[1][2]);
        acc[1][2] = fmaf(a1.z, b2.z, acc[1][2]); acc[1][2] = fmaf(a1.w, b2.w, acc[1][2]);
        acc[1][3] = fmaf(a1.x, b3.x, acc[1][3]); acc[1][3] = fmaf(a1.y, b3.y, acc[1][3]);
        acc[1][3] = fmaf(a1.z, b3.z, acc[1][3]); acc[1][3] = fmaf(a1.w, b3.w, acc[1][3]);
    }
    *(float4*)&Wh[(size_t)i0 * 512 + m0] =
        make_float4(acc[0][0], acc[0][1], acc[0][2], acc[0][3]);
    *(float4*)&Wh[(size_t)(i0 + 1) * 512 + m0] =
        make_float4(acc[1][0], acc[1][1], acc[1][2], acc[1][3]);
}

// ---------- K1b: s2[j] = 0.6 * sum_m a[m] * Wh2[j][m]   (one wave per row)
__global__ __launch_bounds__(256) void k1b_s2(const float* __restrict__ Wh,
                                              const float* __restrict__ a,
                                              float* __restrict__ s2) {
    const int t = threadIdx.x;
    const int lane = t & 63, w = t >> 6;
    const int row = blockIdx.x * 4 + w;
    float4 x = *(const float4*)&Wh[row * 512 + 256 + lane * 4];
    float4 av = *(const float4*)&a[lane * 4];
    float d = x.x * av.x + x.y * av.y + x.z * av.z + x.w * av.w;
#pragma unroll
    for (int off = 32; off > 0; off >>= 1) d += __shfl_xor(d, off);
    if (lane == 0) s2[row] = 0.6f * d;
}

// ---------- K2: partial_z[i][j] = sum_{m in chunk z} b[m]*|Wh1[i][m]+Wh2[j][m]|
// Tile 64i x 64j x 64m, thread 4i x 4j. x1 from global (4-unique), x2 in LDS.
// Grid (16,16,4) = 1024 blocks, single __syncthreads per block.
__global__ __launch_bounds__(256) void k2_scores(const float* __restrict__ Wh,
                                                 const float* __restrict__ a,
                                                 float* __restrict__ sc) {
    __shared__ float X2[64][PAD];
    __shared__ float bsh[64];
    const int bi = blockIdx.x, bj = blockIdx.y, bz = blockIdx.z;
    const int t = threadIdx.x;
    const int ti = t >> 4, tj = t & 15;
    const int i0 = bi * 64 + ti * 4;
    const int j0 = bj * 64 + tj * 4;
    const int m0 = bz * 64;
    const int lr = t >> 2, lc = (t & 3) * 16;
#pragma unroll
    for (int q = 0; q < 4; ++q) {
        *(float4*)&X2[lr][lc + q * 4] =
            *(const float4*)&Wh[(size_t)(bj * 64 + lr) * 512 + 256 + m0 + lc + q * 4];
    }
    if (t < 16) {
        float4 av = *(const float4*)&a[m0 + t * 4];
        *(float4*)&bsh[t * 4] =
            make_float4(0.4f * av.x, 0.4f * av.y, 0.4f * av.z, 0.4f * av.w);
    }
    __syncthreads();
    const float* x1b = Wh + (size_t)i0 * 512 + m0;
    float acc[4][4] = {};
#pragma unroll 4
    for (int k = 0; k < 64; k += 4) {
        float4 x1[4], x2[4];
#pragma unroll
        for (int r = 0; r < 4; ++r) x1[r] = *(const float4*)&x1b[r * 512 + k];
#pragma unroll
        for (int c = 0; c < 4; ++c) x2[c] = *(const float4*)&X2[tj * 4 + c][k];
        const float4 bv = *(const float4*)&bsh[k];
#pragma unroll
        for (int r = 0; r < 4; ++r)
#pragma unroll
            for (int c = 0; c < 4; ++c) {
                acc[r][c] = fmaf(fabsf(x1[r].x + x2[c].x), bv.x, acc[r][c]);
                acc[r][c] = fmaf(fabsf(x1[r].y + x2[c].y), bv.y, acc[r][c]);
                acc[r][c] = fmaf(fabsf(x1[r].z + x2[c].z), bv.z, acc[r][c]);
                acc[r][c] = fmaf(fabsf(x1[r].w + x2[c].w), bv.w, acc[r][c]);
            }
    }
    float* dst = sc + (size_t)bz * (1u << 20);
#pragma unroll
    for (int r = 0; r < 4; ++r) {
        *(float4*)&dst[(size_t)(i0 + r) * 1024 + j0] =
            make_float4(acc[r][0], acc[r][1], acc[r][2], acc[r][3]);
    }
}

// ---------- K3: row softmax of (p0+p1+p2+p3 + s2[j]) -> alpha into sc[0]
__global__ __launch_bounds__(256) void k3_softmax(float* __restrict__ sc,
                                                  const float* __restrict__ s2) {
    const int i = blockIdx.x, t = threadIdx.x;
    __shared__ float red[8];
    const int base = i * 1024 + t * 4;
    float4 v0 = *(float4*)&sc[base];
    float4 v1 = *(const float4*)&sc[(1u << 20) + base];
    float4 v2 = *(const float4*)&sc[(2u << 20) + base];
    float4 v3 = *(const float4*)&sc[(3u << 20) + base];
    float4 vs = *(const float4*)&s2[t * 4];
    float4 v = make_float4(v0.x + v1.x + v2.x + v3.x + vs.x,
                           v0.y + v1.y + v2.y + v3.y + vs.y,
                           v0.z + v1.z + v2.z + v3.z + vs.z,
                           v0.w + v1.w + v2.w + v3.w + vs.w);
    float m = fmaxf(fmaxf(v.x, v.y), fmaxf(v.z, v.w));
#pragma unroll
    for (int off = 32; off > 0; off >>= 1) m = fmaxf(m, __shfl_xor(m, off));
    const int w = t >> 6;
    if ((t & 63) == 0) red[w] = m;
    __syncthreads();
    const float M = fmaxf(fmaxf(red[0], red[1]), fmaxf(red[2], red[3]));
    float4 e;
    e.x = __expf(v.x - M);
    e.y = __expf(v.y - M);
    e.z = __expf(v.z - M);
    e.w = __expf(v.w - M);
    float s = e.x + e.y + e.z + e.w;
#pragma unroll
    for (int off = 32; off > 0; off >>= 1) s += __shfl_xor(s, off);
    if ((t & 63) == 0) red[4 + w] = s;
    __syncthreads();
    const float rs = 1.0f / (red[4] + red[5] + red[6] + red[7]);
    e.x *= rs; e.y *= rs; e.z *= rs; e.w *= rs;
    *(float4*)&sc[base] = e;
}

// ---------- K4: part[s][i][c] = sum_{j in chunk s} alpha[i][j]*HT[c][j]
// Tile 128i x 64c x 64j, thread 8i x 4c. alpha from global (4-unique), HT in LDS.
// Grid (8,4,16) = 512 blocks, single __syncthreads.
__global__ __launch_bounds__(256) void k4_av(const float* __restrict__ alpha,
                                             const float* __restrict__ HT,
                                             float* __restrict__ part) {
    __shared__ float Hs[64][PAD];
    const int bi = blockIdx.x;  // i-tile 0..7 (128 rows)
    const int bc = blockIdx.y;  // c-tile 0..3 (64 cols)
    const int s = blockIdx.z;   // j-chunk 0..15 (64 j)
    const int t = threadIdx.x;
    const int ti = t >> 4, tj = t & 15;
    const int i0 = bi * 128 + ti * 8;
    const int c0 = bc * 64 + tj * 4;
    const int j0 = s * 64;
    const int lr = t >> 2, lc = (t & 3) * 16;
#pragma unroll
    for (int q = 0; q < 4; ++q) {
        *(float4*)&Hs[lr][lc + q * 4] =
            *(const float4*)&HT[(size_t)(bc * 64 + lr) * 1024 + j0 + lc + q * 4];
    }
    __syncthreads();
    const float* ab = alpha + (size_t)i0 * 1024 + j0;
    float acc[8][4] = {};
#pragma unroll 2
    for (int j = 0; j < 64; j += 4) {
        float4 ht[4];
#pragma unroll
        for (int c = 0; c < 4; ++c) ht[c] = *(const float4*)&Hs[tj * 4 + c][j];
#pragma unroll
        for (int r = 0; r < 8; ++r) {
            float4 as = *(const float4*)&ab[r * 1024 + j];
#pragma unroll
            for (int c = 0; c < 4; ++c) {
                acc[r][c] = fmaf(as.x, ht[c].x, acc[r][c]);
                acc[r][c] = fmaf(as.y, ht[c].y, acc[r][c]);
                acc[r][c] = fmaf(as.z, ht[c].z, acc[r][c]);
                acc[r][c] = fmaf(as.w, ht[c].w, acc[r][c]);
            }
        }
    }
#pragma unroll
    for (int r = 0; r < 8; ++r) {
        *(float4*)&part[(size_t)s * 262144 + (size_t)(i0 + r) * 256 + c0] =
            make_float4(acc[r][0], acc[r][1], acc[r][2], acc[r][3]);
    }
}

// ---------- K5: out = sum of 16 partials (out = 1024x256 floats)
__global__ __launch_bounds__(256) void k5_reduce(const float* __restrict__ part,
                                                 float* __restrict__ out) {
    const int idx = (blockIdx.x * 256 + threadIdx.x) * 4;
    float4 o = *(const float4*)&part[idx];
#pragma unroll
    for (int s = 1; s < 16; ++s) {
        float4 p = *(const float4*)&part[(size_t)s * 262144 + idx];
        o.x += p.x; o.y += p.y; o.z += p.z; o.w += p.w;
    }
    *(float4*)&out[idx] = o;
}

extern "C" void kernel_launch(void* const* d_in, const int* in_sizes, int n_in,
                              void* d_out, int out_size, void* d_ws, size_t ws_size,
                              hipStream_t stream) {
    const float* H = (const float*)d_in[0];
    const float* W = (const float*)d_in[1];
    const float* a = (const float*)d_in[2];
    float* out = (float*)d_out;
    float* ws = (float*)d_ws;

    float* sc = ws;                              // 4 x 1M floats (score partials; sc[0] -> alpha)
    float* avp = ws + (4u << 20);                // 16 x 256K floats (AV partials)
    float* Wh = ws + (8u << 20);                 // 512K floats
    float* HT = ws + (8u << 20) + 524288;        // 256K floats
    float* s2 = ws + (8u << 20) + 524288 + 262144;  // 1K floats

    hipLaunchKernelGGL(kT_transpose, dim3(16, 4), dim3(256), 0, stream, H, HT);
    hipLaunchKernelGGL(k1_gemm_wh, dim3(32, 8), dim3(256), 0, stream, H, W, Wh);
    hipLaunchKernelGGL(k1b_s2, dim3(256), dim3(256), 0, stream, Wh, a, s2);
    hipLaunchKernelGGL(k2_scores, dim3(16, 16, 4), dim3(256), 0, stream, Wh, a, sc);
    hipLaunchKernelGGL(k3_softmax, dim3(1024), dim3(256), 0, stream, sc, s2);
    hipLaunchKernelGGL(k4_av, dim3(8, 4, 16), dim3(256), 0, stream, sc, HT, avp);
    hipLaunchKernelGGL(k5_reduce, dim3(256), dim3(256), 0, stream, avp, out);
}

// Round 5
// 72.033 us; speedup vs baseline: 1.2556x; 1.2556x over previous
//
#include <hip/hip_runtime.h>

// GlobalAttention: out = softmax_j(scores) @ H
// scores[i,j] = sum_m lrelu(Wh1[i,m]+Wh2[j,m]) * a[m]
// lrelu(t) = 0.6 t + 0.4|t|; row-constant part drops out of softmax:
// scores'[i,j] = s2[j] + sum_m b[m]*|Wh1[i,m]+Wh2[j,m]|,  b[m]=0.4*a[m].
//
// LDS strides: multiple of 4 floats (keeps float4 reads 16B-aligned) AND an
// odd number of 16B quads (row -> bank-quad is a bijection mod 32, so strided
// row reads are conflict-free). 36 = 9 quads, 68 = 17 quads, 132 = 33 quads.
// All heavy kernels: big per-thread register tiles so VALU ~= LDS issue cost.

#define S36 36
#define S68 68
#define S132 132

// ---------- K1: Whp[z][i][m] = sum_{k in half z} H[i][k] * Wre[m][k]
// Wre[m][k] = W[m&255][(m>>8)*256+k]. 64i x 64m tiles, k-split 2.
// Grid (16, 8, 2) = 256 blocks. R4C4 per thread, k-chunk 32 in LDS.
__global__ __launch_bounds__(256) void k1_gemm_wh(const float* __restrict__ H,
                                                  const float* __restrict__ W,
                                                  float* __restrict__ Whp) {
    __shared__ float As[64][S36];
    __shared__ float Bs[64][S36];
    const int bi = blockIdx.x, bm = blockIdx.y, bz = blockIdx.z;
    const int t = threadIdx.x;
    const int ti = t >> 4, tj = t & 15;
    const int i0 = ti * 4, m0 = tj * 4;
    const int sr = t >> 2, sc4 = (t & 3) * 8;
    const int half = bm >> 2;
    const int kbase = bz * 128;
    float acc[4][4] = {};
    for (int kc = 0; kc < 128; kc += 32) {
        const int kg = kbase + kc;
        *(float4*)&As[sr][sc4] = *(const float4*)&H[(bi * 64 + sr) * 256 + kg + sc4];
        *(float4*)&As[sr][sc4 + 4] =
            *(const float4*)&H[(bi * 64 + sr) * 256 + kg + sc4 + 4];
        const int wrow = (bm * 64 + sr) & 255;
        *(float4*)&Bs[sr][sc4] =
            *(const float4*)&W[wrow * 512 + half * 256 + kg + sc4];
        *(float4*)&Bs[sr][sc4 + 4] =
            *(const float4*)&W[wrow * 512 + half * 256 + kg + sc4 + 4];
        __syncthreads();
#pragma unroll
        for (int k = 0; k < 32; k += 4) {
            float4 a[4], b[4];
#pragma unroll
            for (int r = 0; r < 4; ++r) a[r] = *(const float4*)&As[i0 + r][k];
#pragma unroll
            for (int c = 0; c < 4; ++c) b[c] = *(const float4*)&Bs[m0 + c][k];
#pragma unroll
            for (int r = 0; r < 4; ++r)
#pragma unroll
                for (int c = 0; c < 4; ++c) {
                    acc[r][c] = fmaf(a[r].x, b[c].x, acc[r][c]);
                    acc[r][c] = fmaf(a[r].y, b[c].y, acc[r][c]);
                    acc[r][c] = fmaf(a[r].z, b[c].z, acc[r][c]);
                    acc[r][c] = fmaf(a[r].w, b[c].w, acc[r][c]);
                }
        }
        __syncthreads();
    }
    float* dst = Whp + (size_t)bz * 524288;
#pragma unroll
    for (int r = 0; r < 4; ++r) {
        *(float4*)&dst[(size_t)(bi * 64 + i0 + r) * 512 + bm * 64 + m0] =
            make_float4(acc[r][0], acc[r][1], acc[r][2], acc[r][3]);
    }
}

// ---------- K1b: s2[j] = 0.6 * sum_m a[m] * (Whp0[j][256+m]+Whp1[j][256+m])
__global__ __launch_bounds__(256) void k1b_s2(const float* __restrict__ Whp,
                                              const float* __restrict__ a,
                                              float* __restrict__ s2) {
    const int t = threadIdx.x;
    const int lane = t & 63, w = t >> 6;
    const int row = blockIdx.x * 4 + w;
    const size_t off = (size_t)row * 512 + 256 + lane * 4;
    float4 x0 = *(const float4*)&Whp[off];
    float4 x1 = *(const float4*)&Whp[524288 + off];
    float4 av = *(const float4*)&a[lane * 4];
    float d = (x0.x + x1.x) * av.x + (x0.y + x1.y) * av.y +
              (x0.z + x1.z) * av.z + (x0.w + x1.w) * av.w;
#pragma unroll
    for (int off2 = 32; off2 > 0; off2 >>= 1) d += __shfl_xor(d, off2);
    if (lane == 0) s2[row] = 0.6f * d;
}

// ---------- K2: sc_z[i][j] = sum_{m in chunk z} b[m]*|Wh1[i][m]+Wh2[j][m]|
// Wh = Whp0 + Whp1 merged during staging. Tile 128i x 64j, m-chunk 64.
// Grid (8, 16, 4) = 512 blocks. R8C4 per thread -> LDS:VALU ~ 1.13.
__global__ __launch_bounds__(256) void k2_scores(const float* __restrict__ Whp,
                                                 const float* __restrict__ a,
                                                 float* __restrict__ sc) {
    __shared__ float X1[128][S68];
    __shared__ float X2[64][S68];
    __shared__ float bsh[64];
    const int bi = blockIdx.x, bj = blockIdx.y, bz = blockIdx.z;
    const int t = threadIdx.x;
    const int ti = t >> 4, tj = t & 15;
    const int i0 = ti * 8, j0 = tj * 4;
    const int m0 = bz * 64;
    // stage X1 = Wh1 tile (128 x 64): 8 float4 per thread
    {
        const int r = t >> 1, c = (t & 1) * 32;
        const size_t g = (size_t)(bi * 128 + r) * 512 + m0 + c;
#pragma unroll
        for (int q = 0; q < 8; ++q) {
            float4 p0 = *(const float4*)&Whp[g + q * 4];
            float4 p1 = *(const float4*)&Whp[524288 + g + q * 4];
            X1[r][c + q * 4] = p0.x + p1.x;
            X1[r][c + q * 4 + 1] = p0.y + p1.y;
            X1[r][c + q * 4 + 2] = p0.z + p1.z;
            X1[r][c + q * 4 + 3] = p0.w + p1.w;
        }
    }
    // stage X2 = Wh2 tile (64 x 64): 4 float4 per thread
    {
        const int r = t >> 2, c = (t & 3) * 16;
        const size_t g = (size_t)(bj * 64 + r) * 512 + 256 + m0 + c;
#pragma unroll
        for (int q = 0; q < 4; ++q) {
            float4 p0 = *(const float4*)&Whp[g + q * 4];
            float4 p1 = *(const float4*)&Whp[524288 + g + q * 4];
            X2[r][c + q * 4] = p0.x + p1.x;
            X2[r][c + q * 4 + 1] = p0.y + p1.y;
            X2[r][c + q * 4 + 2] = p0.z + p1.z;
            X2[r][c + q * 4 + 3] = p0.w + p1.w;
        }
    }
    if (t < 16) {
        float4 av = *(const float4*)&a[m0 + t * 4];
        *(float4*)&bsh[t * 4] =
            make_float4(0.4f * av.x, 0.4f * av.y, 0.4f * av.z, 0.4f * av.w);
    }
    __syncthreads();
    float acc[8][4] = {};
#pragma unroll
    for (int k = 0; k < 64; k += 4) {
        float4 x1[8], x2[4];
#pragma unroll
        for (int r = 0; r < 8; ++r) x1[r] = *(const float4*)&X1[i0 + r][k];
#pragma unroll
        for (int c = 0; c < 4; ++c) x2[c] = *(const float4*)&X2[j0 + c][k];
        const float4 bv = *(const float4*)&bsh[k];
#pragma unroll
        for (int r = 0; r < 8; ++r)
#pragma unroll
            for (int c = 0; c < 4; ++c) {
                acc[r][c] = fmaf(fabsf(x1[r].x + x2[c].x), bv.x, acc[r][c]);
                acc[r][c] = fmaf(fabsf(x1[r].y + x2[c].y), bv.y, acc[r][c]);
                acc[r][c] = fmaf(fabsf(x1[r].z + x2[c].z), bv.z, acc[r][c]);
                acc[r][c] = fmaf(fabsf(x1[r].w + x2[c].w), bv.w, acc[r][c]);
            }
    }
    float* dst = sc + (size_t)bz * (1u << 20);
#pragma unroll
    for (int r = 0; r < 8; ++r) {
        *(float4*)&dst[(size_t)(bi * 128 + i0 + r) * 1024 + bj * 64 + j0] =
            make_float4(acc[r][0], acc[r][1], acc[r][2], acc[r][3]);
    }
}

// ---------- K3: row softmax of (sc0+sc1+sc2+sc3 + s2[j]) -> alpha into sc[0]
__global__ __launch_bounds__(256) void k3_softmax(float* __restrict__ sc,
                                                  const float* __restrict__ s2) {
    const int i = blockIdx.x, t = threadIdx.x;
    __shared__ float red[8];
    const int base = i * 1024 + t * 4;
    float4 v0 = *(float4*)&sc[base];
    float4 v1 = *(const float4*)&sc[(1u << 20) + base];
    float4 v2 = *(const float4*)&sc[(2u << 20) + base];
    float4 v3 = *(const float4*)&sc[(3u << 20) + base];
    float4 vs = *(const float4*)&s2[t * 4];
    float4 v = make_float4(v0.x + v1.x + v2.x + v3.x + vs.x,
                           v0.y + v1.y + v2.y + v3.y + vs.y,
                           v0.z + v1.z + v2.z + v3.z + vs.z,
                           v0.w + v1.w + v2.w + v3.w + vs.w);
    float m = fmaxf(fmaxf(v.x, v.y), fmaxf(v.z, v.w));
#pragma unroll
    for (int off = 32; off > 0; off >>= 1) m = fmaxf(m, __shfl_xor(m, off));
    const int w = t >> 6;
    if ((t & 63) == 0) red[w] = m;
    __syncthreads();
    const float M = fmaxf(fmaxf(red[0], red[1]), fmaxf(red[2], red[3]));
    float4 e;
    e.x = __expf(v.x - M);
    e.y = __expf(v.y - M);
    e.z = __expf(v.z - M);
    e.w = __expf(v.w - M);
    float s = e.x + e.y + e.z + e.w;
#pragma unroll
    for (int off = 32; off > 0; off >>= 1) s += __shfl_xor(s, off);
    if ((t & 63) == 0) red[4 + w] = s;
    __syncthreads();
    const float rs = 1.0f / (red[4] + red[5] + red[6] + red[7]);
    e.x *= rs; e.y *= rs; e.z *= rs; e.w *= rs;
    *(float4*)&sc[base] = e;
}

// ---------- K4: avp[s][i][c] = sum_{j in split s} alpha[i][j]*H[j][c]
// Tile 128i x 128c, j-split 16 (64 j per block, two 32-j sub-chunks).
// Grid (8, 2, 16) = 256 blocks. R8C8 per thread -> LDS:VALU ~ 1.5.
__global__ __launch_bounds__(256) void k4_av(const float* __restrict__ alpha,
                                             const float* __restrict__ H,
                                             float* __restrict__ avp) {
    __shared__ float As[128][S36];
    __shared__ float Hs[32][S132];
    const int bi = blockIdx.x, bc = blockIdx.y, bs = blockIdx.z;
    const int t = threadIdx.x;
    const int ti = t >> 4, tj = t & 15;
    const int i0 = ti * 8, c0 = tj * 8;
    float acc[8][8] = {};
#pragma unroll
    for (int sub = 0; sub < 2; ++sub) {
        const int j0 = bs * 64 + sub * 32;
        {
            const int r = t >> 1, c = (t & 1) * 16;
            const size_t g = (size_t)(bi * 128 + r) * 1024 + j0 + c;
#pragma unroll
            for (int q = 0; q < 4; ++q)
                *(float4*)&As[r][c + q * 4] = *(const float4*)&alpha[g + q * 4];
        }
        {
            const int r = t >> 3, c = (t & 7) * 16;
            const size_t g = (size_t)(j0 + r) * 256 + bc * 128 + c;
#pragma unroll
            for (int q = 0; q < 4; ++q)
                *(float4*)&Hs[r][c + q * 4] = *(const float4*)&H[g + q * 4];
        }
        __syncthreads();
#pragma unroll
        for (int jj = 0; jj < 32; jj += 4) {
            float4 av[8], h[4][2];
#pragma unroll
            for (int r = 0; r < 8; ++r) av[r] = *(const float4*)&As[i0 + r][jj];
#pragma unroll
            for (int q = 0; q < 4; ++q) {
                h[q][0] = *(const float4*)&Hs[jj + q][c0];
                h[q][1] = *(const float4*)&Hs[jj + q][c0 + 4];
            }
#pragma unroll
            for (int r = 0; r < 8; ++r) {
                float aq;
#pragma unroll
                for (int q = 0; q < 4; ++q) {
                    aq = (q == 0) ? av[r].x : (q == 1) ? av[r].y
                        : (q == 2) ? av[r].z : av[r].w;
                    acc[r][0] = fmaf(aq, h[q][0].x, acc[r][0]);
                    acc[r][1] = fmaf(aq, h[q][0].y, acc[r][1]);
                    acc[r][2] = fmaf(aq, h[q][0].z, acc[r][2]);
                    acc[r][3] = fmaf(aq, h[q][0].w, acc[r][3]);
                    acc[r][4] = fmaf(aq, h[q][1].x, acc[r][4]);
                    acc[r][5] = fmaf(aq, h[q][1].y, acc[r][5]);
                    acc[r][6] = fmaf(aq, h[q][1].z, acc[r][6]);
                    acc[r][7] = fmaf(aq, h[q][1].w, acc[r][7]);
                }
            }
        }
        __syncthreads();
    }
    float* dst = avp + (size_t)bs * 262144;
#pragma unroll
    for (int r = 0; r < 8; ++r) {
        const size_t o = (size_t)(bi * 128 + i0 + r) * 256 + bc * 128 + c0;
        *(float4*)&dst[o] = make_float4(acc[r][0], acc[r][1], acc[r][2], acc[r][3]);
        *(float4*)&dst[o + 4] = make_float4(acc[r][4], acc[r][5], acc[r][6], acc[r][7]);
    }
}

// ---------- K5: out = sum of 16 partials
__global__ __launch_bounds__(256) void k5_reduce(const float* __restrict__ avp,
                                                 float* __restrict__ out) {
    const int idx = (blockIdx.x * 256 + threadIdx.x) * 4;
    float4 o = *(const float4*)&avp[idx];
#pragma unroll
    for (int s = 1; s < 16; ++s) {
        float4 p = *(const float4*)&avp[(size_t)s * 262144 + idx];
        o.x += p.x; o.y += p.y; o.z += p.z; o.w += p.w;
    }
    *(float4*)&out[idx] = o;
}

extern "C" void kernel_launch(void* const* d_in, const int* in_sizes, int n_in,
                              void* d_out, int out_size, void* d_ws, size_t ws_size,
                              hipStream_t stream) {
    const float* H = (const float*)d_in[0];
    const float* W = (const float*)d_in[1];
    const float* a = (const float*)d_in[2];
    float* out = (float*)d_out;
    float* ws = (float*)d_ws;

    float* sc = ws;                        // 4 x 1M floats (score partials; sc[0] -> alpha)
    float* avp = ws + (4u << 20);          // 16 x 256K floats (AV partials)
    float* Whp = ws + (8u << 20);          // 2 x 512K floats (Wh k-halves)
    float* s2 = ws + (8u << 20) + (1u << 20);  // 1K floats

    hipLaunchKernelGGL(k1_gemm_wh, dim3(16, 8, 2), dim3(256), 0, stream, H, W, Whp);
    hipLaunchKernelGGL(k1b_s2, dim3(256), dim3(256), 0, stream, Whp, a, s2);
    hipLaunchKernelGGL(k2_scores, dim3(8, 16, 4), dim3(256), 0, stream, Whp, a, sc);
    hipLaunchKernelGGL(k3_softmax, dim3(1024), dim3(256), 0, stream, sc, s2);
    hipLaunchKernelGGL(k4_av, dim3(8, 2, 16), dim3(256), 0, stream, sc, H, avp);
    hipLaunchKernelGGL(k5_reduce, dim3(256), dim3(256), 0, stream, avp, out);
}

// Round 6
// 58.864 us; speedup vs baseline: 1.5365x; 1.2237x over previous
//
#include <hip/hip_runtime.h>

// GlobalAttention: out = softmax_j(scores) @ H
// scores[i,j] = sum_m lrelu(Wh1[i,m]+Wh2[j,m]) * a[m]
// lrelu(t) = 0.6t + 0.4|t|; row-constant 0.6*sum(a*Wh1[i]) drops in softmax:
// scores'[i,j] = s2[j] + sum_m b[m]*|Wh1[i,m]+Wh2[j,m]|, b = 0.4a,
// s2[j] = 0.6 * sum_m a[m]*Wh2[j,m].
//
// R6: flash fusion + bank-phase fix.
// LDS rule (bank-quad analysis): a b128 read whose 16 distinct rows step by
// STRIDE_R rows lands in quad-class (STRIDE_R * quads_per_row * lane) mod 8.
// Row-stride-4 reads hit only classes {0,4} -> 8 phases. Fix: per-thread
// column set {tj + 16*c} (row-stride 16 in units of tj) -> classes = tj mod 8,
// 2 addrs/class = 2 phases (free). Broadcast reads (row from ti) are 1 phase.

#define HALF 524288

// ---------- K1: Whp[z][i][m] = sum_{k in half z} H[i][k]*Wre[m][k]
// Wre[m][k] = W[m&255][(m>>8)*256+k]. 64i x 32m tiles, k-split 2.
// Grid (16,16,2) = 512 blocks. Thread: R4 x C2 with m = tj + 16c.
__global__ __launch_bounds__(256) void k1_gemm_wh(const float* __restrict__ H,
                                                  const float* __restrict__ W,
                                                  float* __restrict__ Whp) {
    __shared__ float As[64][36];
    __shared__ float Bs[32][36];
    const int bi = blockIdx.x, bm = blockIdx.y, bz = blockIdx.z;
    const int t = threadIdx.x;
    const int ti = t >> 4, tj = t & 15;
    const int i0 = ti * 4;
    const int half = bm >> 3;
    const int kbase = bz * 128;
    float acc[4][2] = {};
    for (int kc = 0; kc < 128; kc += 32) {
        const int kg = kbase + kc;
        {
            const int r = t >> 2, c = (t & 3) * 8;
            *(float4*)&As[r][c] = *(const float4*)&H[(bi * 64 + r) * 256 + kg + c];
            *(float4*)&As[r][c + 4] =
                *(const float4*)&H[(bi * 64 + r) * 256 + kg + c + 4];
        }
        {
            const int r = t >> 3, c = (t & 7) * 4;
            const int wrow = (bm * 32 + r) & 255;
            *(float4*)&Bs[r][c] =
                *(const float4*)&W[wrow * 512 + half * 256 + kg + c];
        }
        __syncthreads();
#pragma unroll
        for (int k = 0; k < 32; k += 4) {
            float4 a[4], b[2];
#pragma unroll
            for (int r = 0; r < 4; ++r) a[r] = *(const float4*)&As[i0 + r][k];
#pragma unroll
            for (int c = 0; c < 2; ++c) b[c] = *(const float4*)&Bs[tj + 16 * c][k];
#pragma unroll
            for (int r = 0; r < 4; ++r)
#pragma unroll
                for (int c = 0; c < 2; ++c) {
                    acc[r][c] = fmaf(a[r].x, b[c].x, acc[r][c]);
                    acc[r][c] = fmaf(a[r].y, b[c].y, acc[r][c]);
                    acc[r][c] = fmaf(a[r].z, b[c].z, acc[r][c]);
                    acc[r][c] = fmaf(a[r].w, b[c].w, acc[r][c]);
                }
        }
        __syncthreads();
    }
    float* dst = Whp + (size_t)bz * HALF;
#pragma unroll
    for (int r = 0; r < 4; ++r)
#pragma unroll
        for (int c = 0; c < 2; ++c)
            dst[(size_t)(bi * 64 + i0 + r) * 512 + bm * 32 + tj + 16 * c] = acc[r][c];
}

// ---------- K1b: s2[j] = 0.6 * sum_m a[m]*(Whp0[j][256+m]+Whp1[j][256+m])
__global__ __launch_bounds__(256) void k1b_s2(const float* __restrict__ Whp,
                                              const float* __restrict__ a,
                                              float* __restrict__ s2) {
    const int t = threadIdx.x;
    const int lane = t & 63, w = t >> 6;
    const int row = blockIdx.x * 4 + w;
    const size_t off = (size_t)row * 512 + 256 + lane * 4;
    float4 x0 = *(const float4*)&Whp[off];
    float4 x1 = *(const float4*)&Whp[HALF + off];
    float4 av = *(const float4*)&a[lane * 4];
    float d = (x0.x + x1.x) * av.x + (x0.y + x1.y) * av.y +
              (x0.z + x1.z) * av.z + (x0.w + x1.w) * av.w;
#pragma unroll
    for (int o = 32; o > 0; o >>= 1) d += __shfl_xor(d, o);
    if (lane == 0) s2[row] = 0.6f * d;
}

// ---------- KF: flash block = 32 i-rows x 64 j (chunk bj). For its j-chunk:
// scores in regs (m-loop over LDS tiles), local softmax (max/sum over j via
// shfl), P to LDS, PV into avp[bj], m/l to mbuf/lbuf. Grid (32,16)=512 blocks.
__global__ __launch_bounds__(256) void kF_flash(const float* __restrict__ Whp,
                                                const float* __restrict__ a,
                                                const float* __restrict__ s2,
                                                const float* __restrict__ H,
                                                float* __restrict__ avp,
                                                float* __restrict__ mbuf,
                                                float* __restrict__ lbuf) {
    __shared__ float X1[32][68];
    __shared__ float X2[64][68];  // reused as Hs in PV phase
    __shared__ float P[32][68];
    __shared__ float bsh[256];
    const int bi = blockIdx.x, bj = blockIdx.y;
    const int t = threadIdx.x;
    const int ti = t >> 4, tj = t & 15;
    const int i0 = ti * 2;
    if (t < 64) {
        float4 av = *(const float4*)&a[t * 4];
        *(float4*)&bsh[t * 4] =
            make_float4(0.4f * av.x, 0.4f * av.y, 0.4f * av.z, 0.4f * av.w);
    }
    float acc[2][4] = {};
    // -------- scores: acc[r][c] = sum_m b[m]*|Wh1[i0g+r][m] + Wh2[j0g+tj+16c][m]|
    for (int mc = 0; mc < 256; mc += 64) {
        {   // stage X1 (32 x 64): 2 float4/thread, merging k-halves
            const int r = t >> 3, c = (t & 7) * 8;
            const size_t g = (size_t)(bi * 32 + r) * 512 + mc + c;
            float4 p0 = *(const float4*)&Whp[g];
            float4 p1 = *(const float4*)&Whp[HALF + g];
            *(float4*)&X1[r][c] =
                make_float4(p0.x + p1.x, p0.y + p1.y, p0.z + p1.z, p0.w + p1.w);
            float4 q0 = *(const float4*)&Whp[g + 4];
            float4 q1 = *(const float4*)&Whp[HALF + g + 4];
            *(float4*)&X1[r][c + 4] =
                make_float4(q0.x + q1.x, q0.y + q1.y, q0.z + q1.z, q0.w + q1.w);
        }
        {   // stage X2 (64 x 64): 4 float4/thread
            const int r = t >> 2, c = (t & 3) * 16;
            const size_t g = (size_t)(bj * 64 + r) * 512 + 256 + mc + c;
#pragma unroll
            for (int q = 0; q < 4; ++q) {
                float4 p0 = *(const float4*)&Whp[g + q * 4];
                float4 p1 = *(const float4*)&Whp[HALF + g + q * 4];
                *(float4*)&X2[r][c + q * 4] = make_float4(
                    p0.x + p1.x, p0.y + p1.y, p0.z + p1.z, p0.w + p1.w);
            }
        }
        __syncthreads();
#pragma unroll
        for (int k = 0; k < 64; k += 4) {
            float4 x1[2], x2[4];
#pragma unroll
            for (int r = 0; r < 2; ++r) x1[r] = *(const float4*)&X1[i0 + r][k];
#pragma unroll
            for (int c = 0; c < 4; ++c) x2[c] = *(const float4*)&X2[tj + 16 * c][k];
            const float4 bv = *(const float4*)&bsh[mc + k];
#pragma unroll
            for (int r = 0; r < 2; ++r)
#pragma unroll
                for (int c = 0; c < 4; ++c) {
                    acc[r][c] = fmaf(fabsf(x1[r].x + x2[c].x), bv.x, acc[r][c]);
                    acc[r][c] = fmaf(fabsf(x1[r].y + x2[c].y), bv.y, acc[r][c]);
                    acc[r][c] = fmaf(fabsf(x1[r].z + x2[c].z), bv.z, acc[r][c]);
                    acc[r][c] = fmaf(fabsf(x1[r].w + x2[c].w), bv.w, acc[r][c]);
                }
        }
        __syncthreads();
    }
    // -------- add s2[j], local softmax over the 64-j chunk, write P + m/l
#pragma unroll
    for (int c = 0; c < 4; ++c) {
        const float sv = s2[bj * 64 + tj + 16 * c];
        acc[0][c] += sv;
        acc[1][c] += sv;
    }
#pragma unroll
    for (int r = 0; r < 2; ++r) {
        float mm = fmaxf(fmaxf(acc[r][0], acc[r][1]), fmaxf(acc[r][2], acc[r][3]));
        mm = fmaxf(mm, __shfl_xor(mm, 1));
        mm = fmaxf(mm, __shfl_xor(mm, 2));
        mm = fmaxf(mm, __shfl_xor(mm, 4));
        mm = fmaxf(mm, __shfl_xor(mm, 8));
        float l0 = 0.f;
#pragma unroll
        for (int c = 0; c < 4; ++c) {
            acc[r][c] = __expf(acc[r][c] - mm);
            l0 += acc[r][c];
        }
        l0 += __shfl_xor(l0, 1);
        l0 += __shfl_xor(l0, 2);
        l0 += __shfl_xor(l0, 4);
        l0 += __shfl_xor(l0, 8);
#pragma unroll
        for (int c = 0; c < 4; ++c) P[i0 + r][tj + 16 * c] = acc[r][c];
        if (tj == 0) {
            const int gi = bi * 32 + i0 + r;
            mbuf[bj * 1024 + gi] = mm;
            lbuf[bj * 1024 + gi] = l0;
        }
    }
    __syncthreads();
    // -------- PV: avp[bj][i][c] = sum_{j in chunk} P[i][j] * H[j][c]
    for (int cc = 0; cc < 256; cc += 64) {
        {   // stage Hs(=X2) 64j x 64c: 4 float4/thread
            const int r = t >> 2, c = (t & 3) * 16;
            const size_t g = (size_t)(bj * 64 + r) * 256 + cc + c;
#pragma unroll
            for (int q = 0; q < 4; ++q)
                *(float4*)&X2[r][c + q * 4] = *(const float4*)&H[g + q * 4];
        }
        __syncthreads();
        float acc2[2][4] = {};
#pragma unroll
        for (int jj = 0; jj < 64; jj += 4) {
            float4 pv[2], h[4];
#pragma unroll
            for (int r = 0; r < 2; ++r) pv[r] = *(const float4*)&P[i0 + r][jj];
#pragma unroll
            for (int q = 0; q < 4; ++q) h[q] = *(const float4*)&X2[jj + q][tj * 4];
#pragma unroll
            for (int r = 0; r < 2; ++r) {
                acc2[r][0] = fmaf(pv[r].x, h[0].x, acc2[r][0]);
                acc2[r][1] = fmaf(pv[r].x, h[0].y, acc2[r][1]);
                acc2[r][2] = fmaf(pv[r].x, h[0].z, acc2[r][2]);
                acc2[r][3] = fmaf(pv[r].x, h[0].w, acc2[r][3]);
                acc2[r][0] = fmaf(pv[r].y, h[1].x, acc2[r][0]);
                acc2[r][1] = fmaf(pv[r].y, h[1].y, acc2[r][1]);
                acc2[r][2] = fmaf(pv[r].y, h[1].z, acc2[r][2]);
                acc2[r][3] = fmaf(pv[r].y, h[1].w, acc2[r][3]);
                acc2[r][0] = fmaf(pv[r].z, h[2].x, acc2[r][0]);
                acc2[r][1] = fmaf(pv[r].z, h[2].y, acc2[r][1]);
                acc2[r][2] = fmaf(pv[r].z, h[2].z, acc2[r][2]);
                acc2[r][3] = fmaf(pv[r].z, h[2].w, acc2[r][3]);
                acc2[r][0] = fmaf(pv[r].w, h[3].x, acc2[r][0]);
                acc2[r][1] = fmaf(pv[r].w, h[3].y, acc2[r][1]);
                acc2[r][2] = fmaf(pv[r].w, h[3].z, acc2[r][2]);
                acc2[r][3] = fmaf(pv[r].w, h[3].w, acc2[r][3]);
            }
        }
#pragma unroll
        for (int r = 0; r < 2; ++r) {
            *(float4*)&avp[(size_t)bj * 262144 + (size_t)(bi * 32 + i0 + r) * 256 +
                           cc + tj * 4] =
                make_float4(acc2[r][0], acc2[r][1], acc2[r][2], acc2[r][3]);
        }
        __syncthreads();
    }
}

// ---------- KM: merge 16 j-chunks with flash rescaling.
// out[i][c] = sum_s e^{m_s-M} avp[s][i][c] / sum_s e^{m_s-M} l_s
__global__ __launch_bounds__(256) void kM_merge(const float* __restrict__ avp,
                                                const float* __restrict__ mbuf,
                                                const float* __restrict__ lbuf,
                                                float* __restrict__ out) {
    const int t = threadIdx.x;
    const int i = blockIdx.x * 4 + (t >> 6);
    const int c0 = (t & 63) * 4;
    float ms[16], es[16];
    float M = -1e30f;
#pragma unroll
    for (int s = 0; s < 16; ++s) {
        ms[s] = mbuf[s * 1024 + i];
        M = fmaxf(M, ms[s]);
    }
    float L = 0.f;
#pragma unroll
    for (int s = 0; s < 16; ++s) {
        es[s] = __expf(ms[s] - M);
        L = fmaf(es[s], lbuf[s * 1024 + i], L);
    }
    const float inv = 1.0f / L;
    float4 o = make_float4(0.f, 0.f, 0.f, 0.f);
#pragma unroll
    for (int s = 0; s < 16; ++s) {
        float4 p = *(const float4*)&avp[(size_t)s * 262144 + (size_t)i * 256 + c0];
        o.x = fmaf(es[s], p.x, o.x);
        o.y = fmaf(es[s], p.y, o.y);
        o.z = fmaf(es[s], p.z, o.z);
        o.w = fmaf(es[s], p.w, o.w);
    }
    o.x *= inv; o.y *= inv; o.z *= inv; o.w *= inv;
    *(float4*)&out[(size_t)i * 256 + c0] = o;
}

extern "C" void kernel_launch(void* const* d_in, const int* in_sizes, int n_in,
                              void* d_out, int out_size, void* d_ws, size_t ws_size,
                              hipStream_t stream) {
    const float* H = (const float*)d_in[0];
    const float* W = (const float*)d_in[1];
    const float* a = (const float*)d_in[2];
    float* out = (float*)d_out;
    float* ws = (float*)d_ws;

    float* avp = ws;                             // 16 x 262144 floats (16 MB)
    float* mbuf = ws + (4u << 20);               // 16K floats
    float* lbuf = mbuf + 16384;                  // 16K floats
    float* Whp = lbuf + 16384;                   // 2 x 524288 floats
    float* s2 = Whp + 2 * HALF;                  // 1K floats

    hipLaunchKernelGGL(k1_gemm_wh, dim3(16, 16, 2), dim3(256), 0, stream, H, W, Whp);
    hipLaunchKernelGGL(k1b_s2, dim3(256), dim3(256), 0, stream, Whp, a, s2);
    hipLaunchKernelGGL(kF_flash, dim3(32, 16), dim3(256), 0, stream, Whp, a, s2, H,
                       avp, mbuf, lbuf);
    hipLaunchKernelGGL(kM_merge, dim3(256), dim3(256), 0, stream, avp, mbuf, lbuf, out);
}

// Round 7
// 50.179 us; speedup vs baseline: 1.8024x; 1.1731x over previous
//
#include <hip/hip_runtime.h>

// GlobalAttention: out = softmax_j(scores) @ H
// scores[i,j] = sum_m lrelu(Wh1[i,m]+Wh2[j,m]) * a[m]
// lrelu(t) = 0.6t + 0.4|t|; row-constant part drops in softmax:
// scores'[i,j] = s2[j] + sum_m b[m]*|Wh1[i,m]+Wh2[j,m]|, b = 0.4a,
// s2[j] = 0.6 * sum_m a[m]*Wh2[j,m].
//
// R7: software-pipelined kF (T14 async reg-stage + double-buffered LDS +
// raw barriers with counted compiler vmcnt). kW merges k1's k-split halves.
// LDS stride 68 floats = 17 quads (odd) -> strided-row b128 reads conflict-free.

#define HALF 524288
#define LDW 68

#define FENCE_BAR() do {                                   \
    __builtin_amdgcn_sched_barrier(0);                     \
    asm volatile("s_waitcnt lgkmcnt(0)" ::: "memory");     \
    __builtin_amdgcn_s_barrier();                          \
    __builtin_amdgcn_sched_barrier(0);                     \
} while (0)

#define BAR_ONLY() do {                                    \
    __builtin_amdgcn_sched_barrier(0);                     \
    asm volatile("s_waitcnt lgkmcnt(0)" ::: "memory");     \
    __builtin_amdgcn_s_barrier();                          \
    __builtin_amdgcn_sched_barrier(0);                     \
} while (0)

// ---------- K1: Whp[z][i][m] = sum_{k in half z} H[i][k]*Wre[m][k]
// Wre[m][k] = W[m&255][(m>>8)*256+k]. 64i x 32m tiles, k-split 2.
// Grid (16,16,2) = 512 blocks.
__global__ __launch_bounds__(256) void k1_gemm_wh(const float* __restrict__ H,
                                                  const float* __restrict__ W,
                                                  float* __restrict__ Whp) {
    __shared__ float As[64][36];
    __shared__ float Bs[32][36];
    const int bi = blockIdx.x, bm = blockIdx.y, bz = blockIdx.z;
    const int t = threadIdx.x;
    const int ti = t >> 4, tj = t & 15;
    const int i0 = ti * 4;
    const int half = bm >> 3;
    const int kbase = bz * 128;
    float acc[4][2] = {};
    for (int kc = 0; kc < 128; kc += 32) {
        const int kg = kbase + kc;
        {
            const int r = t >> 2, c = (t & 3) * 8;
            *(float4*)&As[r][c] = *(const float4*)&H[(bi * 64 + r) * 256 + kg + c];
            *(float4*)&As[r][c + 4] =
                *(const float4*)&H[(bi * 64 + r) * 256 + kg + c + 4];
        }
        {
            const int r = t >> 3, c = (t & 7) * 4;
            const int wrow = (bm * 32 + r) & 255;
            *(float4*)&Bs[r][c] =
                *(const float4*)&W[wrow * 512 + half * 256 + kg + c];
        }
        __syncthreads();
#pragma unroll
        for (int k = 0; k < 32; k += 4) {
            float4 a[4], b[2];
#pragma unroll
            for (int r = 0; r < 4; ++r) a[r] = *(const float4*)&As[i0 + r][k];
#pragma unroll
            for (int c = 0; c < 2; ++c) b[c] = *(const float4*)&Bs[tj + 16 * c][k];
#pragma unroll
            for (int r = 0; r < 4; ++r)
#pragma unroll
                for (int c = 0; c < 2; ++c) {
                    acc[r][c] = fmaf(a[r].x, b[c].x, acc[r][c]);
                    acc[r][c] = fmaf(a[r].y, b[c].y, acc[r][c]);
                    acc[r][c] = fmaf(a[r].z, b[c].z, acc[r][c]);
                    acc[r][c] = fmaf(a[r].w, b[c].w, acc[r][c]);
                }
        }
        __syncthreads();
    }
    float* dst = Whp + (size_t)bz * HALF;
#pragma unroll
    for (int r = 0; r < 4; ++r)
#pragma unroll
        for (int c = 0; c < 2; ++c)
            dst[(size_t)(bi * 64 + i0 + r) * 512 + bm * 32 + tj + 16 * c] = acc[r][c];
}

// ---------- kW: Wh = Whp0 + Whp1 (merged), s2[j] = 0.6*sum a[m]*Wh2[j][m].
// Grid 512 blocks x 256 thr; block handles 2 rows of 512.
__global__ __launch_bounds__(256) void kW_merge(const float* __restrict__ Whp,
                                                const float* __restrict__ a,
                                                float* __restrict__ Wh,
                                                float* __restrict__ s2) {
    const int t = threadIdx.x;
    const int row = blockIdx.x * 2 + (t >> 7);
    const int col = (t & 127) * 4;
    const size_t off = (size_t)row * 512 + col;
    float4 v0 = *(const float4*)&Whp[off];
    float4 v1 = *(const float4*)&Whp[HALF + off];
    float4 v = make_float4(v0.x + v1.x, v0.y + v1.y, v0.z + v1.z, v0.w + v1.w);
    *(float4*)&Wh[off] = v;
    if (col >= 256) {
        float4 av = *(const float4*)&a[col - 256];
        float p = av.x * v.x + av.y * v.y + av.z * v.z + av.w * v.w;
#pragma unroll
        for (int o = 32; o > 0; o >>= 1) p += __shfl_xor(p, o);
        if ((t & 63) == 0) s2[row] = 0.6f * p;
    }
}

// ---------- KF: flash block = 32 i x 64 j. Pipelined score + softmax + PV.
// Grid (32,16) = 512 blocks, 256 thr.
__global__ __launch_bounds__(256) void kF_flash(const float* __restrict__ Wh,
                                                const float* __restrict__ a,
                                                const float* __restrict__ s2,
                                                const float* __restrict__ H,
                                                float* __restrict__ avp,
                                                float* __restrict__ mbuf,
                                                float* __restrict__ lbuf) {
    __shared__ float X1[2][32][LDW];
    __shared__ float X2[2][64][LDW];
    __shared__ float P[32][LDW];
    __shared__ float bsh[256];
    const int bi = blockIdx.x, bj = blockIdx.y;
    const int t = threadIdx.x;
    const int ti = t >> 4, tj = t & 15;
    const int i0 = ti * 2;
    // staging coords
    const int r1 = t >> 3, c1 = (t & 7) * 8;   // X1 tile 32x64: 2 f4/thread
    const int r2 = t >> 2, c2 = (t & 3) * 16;  // X2 tile 64x64: 4 f4/thread
    const float* g1 = Wh + (size_t)(bi * 32 + r1) * 512 + c1;
    const float* g2 = Wh + (size_t)(bj * 64 + r2) * 512 + 256 + c2;
    const float* gH = H + (size_t)(bj * 64 + r2) * 256 + c2;

    float4 A0, A1, A2, A3, A4, A5, B0, B1, B2, B3, B4, B5;

#define LOADC_A(mc) do { A0 = *(const float4*)(g1 + (mc)*64); \
    A1 = *(const float4*)(g1 + (mc)*64 + 4);                  \
    A2 = *(const float4*)(g2 + (mc)*64);                      \
    A3 = *(const float4*)(g2 + (mc)*64 + 4);                  \
    A4 = *(const float4*)(g2 + (mc)*64 + 8);                  \
    A5 = *(const float4*)(g2 + (mc)*64 + 12); } while (0)
#define LOADC_B(mc) do { B0 = *(const float4*)(g1 + (mc)*64); \
    B1 = *(const float4*)(g1 + (mc)*64 + 4);                  \
    B2 = *(const float4*)(g2 + (mc)*64);                      \
    B3 = *(const float4*)(g2 + (mc)*64 + 4);                  \
    B4 = *(const float4*)(g2 + (mc)*64 + 8);                  \
    B5 = *(const float4*)(g2 + (mc)*64 + 12); } while (0)
#define WRITEC_A(buf) do { *(float4*)&X1[buf][r1][c1] = A0;   \
    *(float4*)&X1[buf][r1][c1 + 4] = A1;                      \
    *(float4*)&X2[buf][r2][c2] = A2;                          \
    *(float4*)&X2[buf][r2][c2 + 4] = A3;                      \
    *(float4*)&X2[buf][r2][c2 + 8] = A4;                      \
    *(float4*)&X2[buf][r2][c2 + 12] = A5; } while (0)
#define WRITEC_B(buf) do { *(float4*)&X1[buf][r1][c1] = B0;   \
    *(float4*)&X1[buf][r1][c1 + 4] = B1;                      \
    *(float4*)&X2[buf][r2][c2] = B2;                          \
    *(float4*)&X2[buf][r2][c2 + 4] = B3;                      \
    *(float4*)&X2[buf][r2][c2 + 8] = B4;                      \
    *(float4*)&X2[buf][r2][c2 + 12] = B5; } while (0)

    // prologue: issue chunk 0, set up bsh, preload s2
    LOADC_A(0);
    float s2v0 = s2[bj * 64 + tj];
    float s2v1 = s2[bj * 64 + tj + 16];
    float s2v2 = s2[bj * 64 + tj + 32];
    float s2v3 = s2[bj * 64 + tj + 48];
    if (t < 64) {
        float4 av = *(const float4*)&a[t * 4];
        *(float4*)&bsh[t * 4] =
            make_float4(0.4f * av.x, 0.4f * av.y, 0.4f * av.z, 0.4f * av.w);
    }

    float acc[2][4] = {};
#pragma unroll
    for (int mc = 0; mc < 4; ++mc) {
        const int buf = mc & 1;
        if (mc < 3) {                    // issue next chunk first (stays in flight)
            if (buf == 0) LOADC_B(mc + 1); else LOADC_A(mc + 1);
        }
        if (buf == 0) WRITEC_A(0); else WRITEC_B(1);  // waits own chunk (counted)
        FENCE_BAR();
#pragma unroll
        for (int k = 0; k < 64; k += 4) {
            float4 x1[2], x2[4];
#pragma unroll
            for (int r = 0; r < 2; ++r) x1[r] = *(const float4*)&X1[buf][i0 + r][k];
#pragma unroll
            for (int c = 0; c < 4; ++c)
                x2[c] = *(const float4*)&X2[buf][tj + 16 * c][k];
            const float4 bv = *(const float4*)&bsh[mc * 64 + k];
#pragma unroll
            for (int r = 0; r < 2; ++r)
#pragma unroll
                for (int c = 0; c < 4; ++c) {
                    acc[r][c] = fmaf(fabsf(x1[r].x + x2[c].x), bv.x, acc[r][c]);
                    acc[r][c] = fmaf(fabsf(x1[r].y + x2[c].y), bv.y, acc[r][c]);
                    acc[r][c] = fmaf(fabsf(x1[r].z + x2[c].z), bv.z, acc[r][c]);
                    acc[r][c] = fmaf(fabsf(x1[r].w + x2[c].w), bv.w, acc[r][c]);
                }
        }
        BAR_ONLY();
    }

    // add s2 (loads long since resolved; nothing else outstanding here)
    acc[0][0] += s2v0; acc[1][0] += s2v0;
    acc[0][1] += s2v1; acc[1][1] += s2v1;
    acc[0][2] += s2v2; acc[1][2] += s2v2;
    acc[0][3] += s2v3; acc[1][3] += s2v3;

    // issue PV chunk 0 (H) into regs A while softmax runs
    A2 = *(const float4*)(gH);
    A3 = *(const float4*)(gH + 4);
    A4 = *(const float4*)(gH + 8);
    A5 = *(const float4*)(gH + 12);

    // local softmax over this 64-j chunk
    float mm0, mm1, l00, l01;
#pragma unroll
    for (int r = 0; r < 2; ++r) {
        float mm = fmaxf(fmaxf(acc[r][0], acc[r][1]), fmaxf(acc[r][2], acc[r][3]));
        mm = fmaxf(mm, __shfl_xor(mm, 1));
        mm = fmaxf(mm, __shfl_xor(mm, 2));
        mm = fmaxf(mm, __shfl_xor(mm, 4));
        mm = fmaxf(mm, __shfl_xor(mm, 8));
        float l0 = 0.f;
#pragma unroll
        for (int c = 0; c < 4; ++c) {
            acc[r][c] = __expf(acc[r][c] - mm);
            l0 += acc[r][c];
        }
        l0 += __shfl_xor(l0, 1);
        l0 += __shfl_xor(l0, 2);
        l0 += __shfl_xor(l0, 4);
        l0 += __shfl_xor(l0, 8);
#pragma unroll
        for (int c = 0; c < 4; ++c) P[i0 + r][tj + 16 * c] = acc[r][c];
        if (r == 0) { mm0 = mm; l00 = l0; } else { mm1 = mm; l01 = l0; }
    }
    FENCE_BAR();  // P visible to all

    // PV: avp[bj][i][c] = sum_j P[i][j]*H[j][c], pipelined over 4 c-chunks.
#pragma unroll
    for (int cc = 0; cc < 4; ++cc) {
        const int buf = cc & 1;
        if (cc < 3) {   // issue next H chunk
            if (buf == 0) {
                B2 = *(const float4*)(gH + (cc + 1) * 64);
                B3 = *(const float4*)(gH + (cc + 1) * 64 + 4);
                B4 = *(const float4*)(gH + (cc + 1) * 64 + 8);
                B5 = *(const float4*)(gH + (cc + 1) * 64 + 12);
            } else {
                A2 = *(const float4*)(gH + (cc + 1) * 64);
                A3 = *(const float4*)(gH + (cc + 1) * 64 + 4);
                A4 = *(const float4*)(gH + (cc + 1) * 64 + 8);
                A5 = *(const float4*)(gH + (cc + 1) * 64 + 12);
            }
        }
        if (buf == 0) {
            *(float4*)&X2[0][r2][c2] = A2;
            *(float4*)&X2[0][r2][c2 + 4] = A3;
            *(float4*)&X2[0][r2][c2 + 8] = A4;
            *(float4*)&X2[0][r2][c2 + 12] = A5;
        } else {
            *(float4*)&X2[1][r2][c2] = B2;
            *(float4*)&X2[1][r2][c2 + 4] = B3;
            *(float4*)&X2[1][r2][c2 + 8] = B4;
            *(float4*)&X2[1][r2][c2 + 12] = B5;
        }
        FENCE_BAR();
        float acc2[2][4] = {};
#pragma unroll
        for (int jj = 0; jj < 64; jj += 4) {
            float4 pv[2], h[4];
#pragma unroll
            for (int r = 0; r < 2; ++r) pv[r] = *(const float4*)&P[i0 + r][jj];
#pragma unroll
            for (int q = 0; q < 4; ++q)
                h[q] = *(const float4*)&X2[buf][jj + q][tj * 4];
#pragma unroll
            for (int r = 0; r < 2; ++r) {
                acc2[r][0] = fmaf(pv[r].x, h[0].x, acc2[r][0]);
                acc2[r][1] = fmaf(pv[r].x, h[0].y, acc2[r][1]);
                acc2[r][2] = fmaf(pv[r].x, h[0].z, acc2[r][2]);
                acc2[r][3] = fmaf(pv[r].x, h[0].w, acc2[r][3]);
                acc2[r][0] = fmaf(pv[r].y, h[1].x, acc2[r][0]);
                acc2[r][1] = fmaf(pv[r].y, h[1].y, acc2[r][1]);
                acc2[r][2] = fmaf(pv[r].y, h[1].z, acc2[r][2]);
                acc2[r][3] = fmaf(pv[r].y, h[1].w, acc2[r][3]);
                acc2[r][0] = fmaf(pv[r].z, h[2].x, acc2[r][0]);
                acc2[r][1] = fmaf(pv[r].z, h[2].y, acc2[r][1]);
                acc2[r][2] = fmaf(pv[r].z, h[2].z, acc2[r][2]);
                acc2[r][3] = fmaf(pv[r].z, h[2].w, acc2[r][3]);
                acc2[r][0] = fmaf(pv[r].w, h[3].x, acc2[r][0]);
                acc2[r][1] = fmaf(pv[r].w, h[3].y, acc2[r][1]);
                acc2[r][2] = fmaf(pv[r].w, h[3].z, acc2[r][2]);
                acc2[r][3] = fmaf(pv[r].w, h[3].w, acc2[r][3]);
            }
        }
#pragma unroll
        for (int r = 0; r < 2; ++r) {
            *(float4*)&avp[(size_t)bj * 262144 + (size_t)(bi * 32 + i0 + r) * 256 +
                           cc * 64 + tj * 4] =
                make_float4(acc2[r][0], acc2[r][1], acc2[r][2], acc2[r][3]);
        }
        BAR_ONLY();
    }
    if (tj == 0) {
        const int gi = bi * 32 + i0;
        mbuf[bj * 1024 + gi] = mm0;
        lbuf[bj * 1024 + gi] = l00;
        mbuf[bj * 1024 + gi + 1] = mm1;
        lbuf[bj * 1024 + gi + 1] = l01;
    }
#undef LOADC_A
#undef LOADC_B
#undef WRITEC_A
#undef WRITEC_B
}

// ---------- KM: merge 16 j-chunks with flash rescaling.
__global__ __launch_bounds__(256) void kM_merge(const float* __restrict__ avp,
                                                const float* __restrict__ mbuf,
                                                const float* __restrict__ lbuf,
                                                float* __restrict__ out) {
    const int t = threadIdx.x;
    const int i = blockIdx.x * 4 + (t >> 6);
    const int c0 = (t & 63) * 4;
    float ms[16], es[16];
    float M = -1e30f;
#pragma unroll
    for (int s = 0; s < 16; ++s) {
        ms[s] = mbuf[s * 1024 + i];
        M = fmaxf(M, ms[s]);
    }
    float L = 0.f;
#pragma unroll
    for (int s = 0; s < 16; ++s) {
        es[s] = __expf(ms[s] - M);
        L = fmaf(es[s], lbuf[s * 1024 + i], L);
    }
    const float inv = 1.0f / L;
    float4 o = make_float4(0.f, 0.f, 0.f, 0.f);
#pragma unroll
    for (int s = 0; s < 16; ++s) {
        float4 p = *(const float4*)&avp[(size_t)s * 262144 + (size_t)i * 256 + c0];
        o.x = fmaf(es[s], p.x, o.x);
        o.y = fmaf(es[s], p.y, o.y);
        o.z = fmaf(es[s], p.z, o.z);
        o.w = fmaf(es[s], p.w, o.w);
    }
    o.x *= inv; o.y *= inv; o.z *= inv; o.w *= inv;
    *(float4*)&out[(size_t)i * 256 + c0] = o;
}

extern "C" void kernel_launch(void* const* d_in, const int* in_sizes, int n_in,
                              void* d_out, int out_size, void* d_ws, size_t ws_size,
                              hipStream_t stream) {
    const float* H = (const float*)d_in[0];
    const float* W = (const float*)d_in[1];
    const float* a = (const float*)d_in[2];
    float* out = (float*)d_out;
    float* ws = (float*)d_ws;

    // avp (16 x 262144 = 4M floats) aliases Whp (2 x 524288 = 1M floats):
    // Whp is dead after kW_merge, before kF writes avp.
    float* avp = ws;                     // 16 MB
    float* Whp = ws;                     // 4 MB (k1 out, kW in)
    float* Wh = ws + (4u << 20);         // 2 MB merged
    float* mbuf = Wh + HALF;             // 16K floats
    float* lbuf = mbuf + 16384;          // 16K floats
    float* s2 = lbuf + 16384;            // 1K floats

    hipLaunchKernelGGL(k1_gemm_wh, dim3(16, 16, 2), dim3(256), 0, stream, H, W, Whp);
    hipLaunchKernelGGL(kW_merge, dim3(512), dim3(256), 0, stream, Whp, a, Wh, s2);
    hipLaunchKernelGGL(kF_flash, dim3(32, 16), dim3(256), 0, stream, Wh, a, s2, H,
                       avp, mbuf, lbuf);
    hipLaunchKernelGGL(kM_merge, dim3(256), dim3(256), 0, stream, avp, mbuf, lbuf, out);
}